// Round 8
// baseline (273.650 us; speedup 1.0000x reference)
//
#include <hip/hip_runtime.h>
#include <hip/hip_bf16.h>

// Problem constants
#define SZ    2048
#define SLEN  128
#define DWE   100
#define DPE   5
#define DEE   100
#define DC    300
#define CIN   210
#define KLOC  10
#define OUTW  1500
#define DR    34

// GEMM layout: word(100)+pos1(5)+pos2(5)=110 channels via MFMA; event channels analytic.
#define KP    128    // padded K
#define LCOLS 136    // XT row stride (272 B -> ~2-way bank alias on b128, free)
#define LROWS 130    // 128 tokens + 2 zero pad rows
#define CPAD  320    // padded out-channels
#define G     8      // samples per block (grid = SZ/G = 256 = 1 block/CU, no tail)

typedef short short8 __attribute__((ext_vector_type(8)));
typedef float f32x4 __attribute__((ext_vector_type(4)));

static __device__ __forceinline__ unsigned short f2b(float f) {
  return __builtin_bit_cast(unsigned short, __float2bfloat16(f));
}

static __device__ __forceinline__ unsigned cvt_pk_bf16(float lo, float hi) {
  unsigned r;
  asm volatile("v_cvt_pk_bf16_f32 %0, %1, %2" : "=v"(r) : "v"(lo), "v"(hi));
  return r;
}

// fast tanh: (e^2x-1)/(e^2x+1)
static __device__ __forceinline__ float ftanh(float x) {
  x = fminf(fmaxf(x, -15.f), 15.f);
  float e = __expf(2.0f * x);
  return (e - 1.0f) * __builtin_amdgcn_rcpf(e + 1.0f);
}

// wk[kk][c][i] bf16 [3][320][128]; real for c<300, i<110, else 0
__global__ void prep_wk(const float* __restrict__ conv_w, unsigned short* __restrict__ wk) {
  int idx = blockIdx.x * 256 + threadIdx.x;
  if (idx >= 3 * CPAD * KP) return;
  int i  = idx & (KP - 1);
  int c  = (idx / KP) % CPAD;
  int kk = idx / (KP * CPAD);
  float v = 0.f;
  if (c < DC && i < 110) v = conv_w[(c * CIN + i) * 3 + kk];
  wk[idx] = f2b(v);
}

// evconv[st][kk][c] fp32 (+bias folded into kk==1); 4 threads/output + quad reduce
__global__ void prep_ev(const float* __restrict__ conv_w, const float* __restrict__ event_emb,
                        const float* __restrict__ conv_b, float* __restrict__ evconv) {
  int gid = blockIdx.x * 256 + threadIdx.x;
  int o = gid >> 2, sub = gid & 3;
  if (o >= DR * 3 * DC) return;
  int c  = o % DC;
  int kk = (o / DC) % 3;
  int st = o / (3 * DC);
  float v = 0.f;
  if (st != 0) {
    const float* wrow = conv_w + (c * CIN + 110) * 3 + kk;
    const float* e = event_emb + st * DEE;
    #pragma unroll
    for (int i = 0; i < 25; ++i) v += wrow[3 * (sub * 25 + i)] * e[sub * 25 + i];
  }
  v += __shfl_xor(v, 1);
  v += __shfl_xor(v, 2);
  if (sub == 0) evconv[o] = v + (kk == 1 ? conv_b[c] : 0.f);
}

// loc_embeds: out[s][900..1499]; independent of the conv path -> own streaming kernel
__global__ void loc_kernel(const int* __restrict__ loc, const int* __restrict__ loc_mark,
                           const float* __restrict__ word_emb, float* __restrict__ out) {
  int gid = blockIdx.x * 256 + threadIdx.x;
  if (gid >= SZ * 600) return;
  int s = gid / 600, j = gid % 600;
  const int mark = loc_mark[s];
  float v;
  if (j < 400) {
    const int k = j / 100, d = j % 100;
    const int idx = loc[s * KLOC + k];
    v = (idx == 0) ? 0.f : word_emb[(size_t)idx * DWE + d];
  } else if (j < 500) {
    const int d = j - 400;
    float sum = 0.f;
    for (int k = 4; k < 4 + mark; ++k) {
      const int idx = loc[s * KLOC + k];
      sum += (idx == 0) ? 0.f : word_emb[(size_t)idx * DWE + d];
    }
    v = sum / (float)mark;
  } else {
    const int d = j - 500;
    const int idx = loc[s * KLOC + 4 + mark];
    v = (idx == 0) ? 0.f : word_emb[(size_t)idx * DWE + d];
  }
  out[(size_t)s * OUTW + 900 + j] = ftanh(v);
}

// (512,2): 256-reg budget — deliberately generous (round-5: an under-budget
// allocator spills the acc tile to scratch = catastrophe). Occupancy is 1
// block/CU either way; latency hiding comes from the explicit G-sample pipeline.
__global__ __launch_bounds__(512, 2) void dmcnn_main(
    const int* __restrict__ inp, const int* __restrict__ pos1, const int* __restrict__ pos2,
    const int* __restrict__ subtype,
    const float* __restrict__ maskL, const float* __restrict__ maskM,
    const float* __restrict__ word_emb, const float* __restrict__ pos_emb,
    const unsigned short* __restrict__ wk, const float* __restrict__ evconv,
    float* __restrict__ out)
{
  __shared__ unsigned short XT[LROWS * LCOLS];  // 35360 B; XT[t+1][i]
  __shared__ float pool[2 * 304 * 3];           // 7296 B; [wt][c][{L,M,R}]
  __shared__ int cwbuf[2][4];                   // ping-pong cut-point popcounts

  const int tid = threadIdx.x;
  const int t = tid >> 2, q = tid & 3;          // staging role: 4 threads/token
  const int wv = tid >> 6, wc = wv & 3, wt = wv >> 2;
  const int lane = tid & 63, r16 = lane & 15, q16 = lane >> 4;
  const int s0 = blockIdx.x * G;

  // ---- one-time LDS init: pad rows 0/129 and K-pad cols 110..127 ----
  if (tid < 64)       ((unsigned*)XT)[tid] = 0u;
  else if (tid < 128) ((unsigned*)(XT + 129 * LCOLS))[tid - 64] = 0u;
  for (int i = tid; i < 128 * 9; i += 512) {
    int rr = i / 9, dd = i % 9;
    *(unsigned*)&XT[(rr + 1) * LCOLS + 110 + 2 * dd] = 0u;
  }

  // ---- prologue: stage sample 0 synchronously; preload stage-indices for g=1 ----
  int w_stage = inp[s0 * SLEN + t];
  int p_stage = 0;
  if (q == 1)      p_stage = pos1[s0 * SLEN + t];
  else if (q == 2) p_stage = pos2[s0 * SLEN + t];
  float mLs = 0.f, mMs = 0.f;
  if (tid < 128) { mLs = maskL[s0 * SLEN + tid]; mMs = maskM[s0 * SLEN + tid]; }
  int st_cur = subtype[s0];
  int st_nxt = subtype[s0 + 1];

  {
    const float4* wp = (const float4*)(word_emb + (size_t)w_stage * DWE);
    float4 v0[7];
    #pragma unroll
    for (int jj = 0; jj < 7; ++jj) { int j = q + 4 * jj; if (j < 25) v0[jj] = wp[j]; }
    float pv0[5];
    if (q == 1 || q == 2) {
      const float* pp = pos_emb + p_stage * DPE;
      #pragma unroll
      for (int d = 0; d < 5; ++d) pv0[d] = pp[d];
    }
    unsigned short* row = &XT[(t + 1) * LCOLS];
    #pragma unroll
    for (int jj = 0; jj < 7; ++jj) {
      int j = q + 4 * jj;
      if (j < 25) {
        unsigned lo = cvt_pk_bf16(v0[jj].x, v0[jj].y);
        unsigned hi = cvt_pk_bf16(v0[jj].z, v0[jj].w);
        if (w_stage == 0) { lo = 0u; hi = 0u; }   // padding_idx=0
        *(uint2*)&row[4 * j] = make_uint2(lo, hi);
      }
    }
    if (q == 1 || q == 2) {
      #pragma unroll
      for (int d = 0; d < 5; ++d) row[DWE + (q - 1) * DPE + d] = f2b(pv0[d]);
    }
    if (tid < 128) {  // cuts for sample 0
      unsigned long long bL = __ballot(mLs > 0.5f);
      unsigned long long bM = __ballot(mMs > 0.5f);
      if ((tid & 63) == 0) {
        cwbuf[0][tid >> 6]       = __popcll(bL);
        cwbuf[0][2 + (tid >> 6)] = __popcll(bM);
      }
    }
    // stage-indices for sample 1
    w_stage = inp[(s0 + 1) * SLEN + t];
    if (q == 1)      p_stage = pos1[(s0 + 1) * SLEN + t];
    else if (q == 2) p_stage = pos2[(s0 + 1) * SLEN + t];
    if (tid < 128) { mLs = maskL[(s0 + 1) * SLEN + tid]; mMs = maskM[(s0 + 1) * SLEN + tid]; }
  }
  __syncthreads();

  const unsigned short* wbase = wk + (size_t)(80 * wc + r16) * KP + q16 * 8;
  float4 v[7];
  float pv[5];

  #pragma unroll 1
  for (int g = 0; g < G; ++g) {
    // ---- (b) issue next sample's gathers into registers (in flight under GEMM) ----
    if (g + 1 < G) {
      const float4* wp = (const float4*)(word_emb + (size_t)w_stage * DWE);
      #pragma unroll
      for (int jj = 0; jj < 7; ++jj) { int j = q + 4 * jj; if (j < 25) v[jj] = wp[j]; }
      if (q == 1 || q == 2) {
        const float* pp = pos_emb + p_stage * DPE;
        #pragma unroll
        for (int d = 0; d < 5; ++d) pv[d] = pp[d];
      }
    }

    // ---- (c) GEMM: wave (wc,wt): channels [80wc,+80) x tokens [64wt,+64) ----
    f32x4 acc[4][5];
    #pragma unroll
    for (int tt = 0; tt < 4; ++tt)
      #pragma unroll
      for (int ci = 0; ci < 5; ++ci) acc[tt][ci] = (f32x4){0.f, 0.f, 0.f, 0.f};

    #pragma unroll 1
    for (int ks = 0; ks < 12; ++ks) {
      const int kk = ks >> 2, kt = ks & 3;
      short8 wf[5];
      #pragma unroll
      for (int ci = 0; ci < 5; ++ci)
        wf[ci] = *(const short8*)(wbase + (size_t)(kk * CPAD + 16 * ci) * KP + kt * 32);
      #pragma unroll
      for (int tt = 0; tt < 4; ++tt) {
        short8 xf = *(const short8*)&XT[(64 * wt + 16 * tt + r16 + kk) * LCOLS + kt * 32 + q16 * 8];
        #pragma unroll
        for (int ci = 0; ci < 5; ++ci)
          acc[tt][ci] = __builtin_amdgcn_mfma_f32_16x16x32_bf16(xf, wf[ci], acc[tt][ci], 0, 0, 0);
      }
    }

    // ---- (d) per-wave pooled max into LDS pool ----
    const int acut = cwbuf[g & 1][0] + cwbuf[g & 1][1];
    const int bcut = acut + cwbuf[g & 1][2] + cwbuf[g & 1][3];
    const float* evc = evconv + (size_t)st_cur * 3 * DC;

    #pragma unroll
    for (int ci = 0; ci < 5; ++ci) {
      const int c = 80 * wc + 16 * ci + r16;
      const int cc = c < DC ? c : 0;
      const float e0 = evc[cc], e1 = evc[cc + DC], e2 = evc[cc + 2 * DC];
      const float base = e0 + e1 + e2;   // bias folded into e1
      float rL = 0.f, rM = 0.f, rR = 0.f;
      #pragma unroll
      for (int tt = 0; tt < 4; ++tt) {
        #pragma unroll
        for (int j = 0; j < 4; ++j) {
          const int tt_abs = 64 * wt + 16 * tt + 4 * q16 + j;
          float x = acc[tt][ci][j] + base;
          if (tt_abs == 0)   x -= e0;
          if (tt_abs == 127) x -= e2;
          if (tt_abs < acut)      rL = fmaxf(rL, x);
          else if (tt_abs < bcut) rM = fmaxf(rM, x);
          else                    rR = fmaxf(rR, x);
        }
      }
      #pragma unroll
      for (int off = 16; off < 64; off <<= 1) {
        rL = fmaxf(rL, __shfl_xor(rL, off));
        rM = fmaxf(rM, __shfl_xor(rM, off));
        rR = fmaxf(rR, __shfl_xor(rR, off));
      }
      if (q16 == 0 && c < DC) {
        float* p = pool + ((size_t)wt * 304 + c) * 3;
        p[0] = rL; p[1] = rM; p[2] = rR;
      }
    }
    // cuts for sample g+1
    if (g + 1 < G && tid < 128) {
      unsigned long long bL = __ballot(mLs > 0.5f);
      unsigned long long bM = __ballot(mMs > 0.5f);
      if ((tid & 63) == 0) {
        cwbuf[(g + 1) & 1][tid >> 6]       = __popcll(bL);
        cwbuf[(g + 1) & 1][2 + (tid >> 6)] = __popcll(bM);
      }
    }
    __syncthreads();

    // ---- (e) store outputs g; write XT for g+1; preload indices for g+2 ----
    float* orow = out + (size_t)(s0 + g) * OUTW;
    if (tid < DC) {
      const float* p0 = pool + (size_t)tid * 3;
      const float* p1 = pool + (size_t)(304 + tid) * 3;
      orow[tid]          = ftanh(fmaxf(p0[0], p1[0]));
      orow[DC + tid]     = ftanh(fmaxf(p0[1], p1[1]));
      orow[2 * DC + tid] = ftanh(fmaxf(p0[2], p1[2]));
    }
    if (g + 1 < G) {
      unsigned short* row = &XT[(t + 1) * LCOLS];
      #pragma unroll
      for (int jj = 0; jj < 7; ++jj) {
        int j = q + 4 * jj;
        if (j < 25) {
          unsigned lo = cvt_pk_bf16(v[jj].x, v[jj].y);
          unsigned hi = cvt_pk_bf16(v[jj].z, v[jj].w);
          if (w_stage == 0) { lo = 0u; hi = 0u; }
          *(uint2*)&row[4 * j] = make_uint2(lo, hi);
        }
      }
      if (q == 1 || q == 2) {
        #pragma unroll
        for (int d = 0; d < 5; ++d) row[DWE + (q - 1) * DPE + d] = f2b(pv[d]);
      }
      st_cur = st_nxt;
      if (g + 2 < G) {
        w_stage = inp[(s0 + g + 2) * SLEN + t];
        if (q == 1)      p_stage = pos1[(s0 + g + 2) * SLEN + t];
        else if (q == 2) p_stage = pos2[(s0 + g + 2) * SLEN + t];
        if (tid < 128) { mLs = maskL[(s0 + g + 2) * SLEN + tid]; mMs = maskM[(s0 + g + 2) * SLEN + tid]; }
        st_nxt = subtype[s0 + g + 2];
      }
    }
    __syncthreads();
  }
}

extern "C" void kernel_launch(void* const* d_in, const int* in_sizes, int n_in,
                              void* d_out, int out_size, void* d_ws, size_t ws_size,
                              hipStream_t stream) {
  const int*   inp       = (const int*)d_in[0];
  const int*   pos1      = (const int*)d_in[1];
  const int*   pos2      = (const int*)d_in[2];
  const int*   loc       = (const int*)d_in[3];
  const int*   loc_mark  = (const int*)d_in[4];
  const int*   subtype   = (const int*)d_in[5];
  const float* maskL     = (const float*)d_in[6];
  const float* maskM     = (const float*)d_in[7];
  // maskR (d_in[8]) unused: R-segment is derived from the L/M cut points
  const float* word_emb  = (const float*)d_in[9];
  const float* pos_emb   = (const float*)d_in[10];
  const float* event_emb = (const float*)d_in[11];
  const float* conv_w    = (const float*)d_in[12];
  const float* conv_b    = (const float*)d_in[13];

  unsigned short* wk = (unsigned short*)d_ws;                    // 245760 B
  float* evconv = (float*)((char*)d_ws + 3 * CPAD * KP * 2);     // 122400 B
  float* out = (float*)d_out;

  prep_wk<<<(3 * CPAD * KP + 255) / 256, 256, 0, stream>>>(conv_w, wk);
  prep_ev<<<(DR * 3 * DC * 4 + 255) / 256, 256, 0, stream>>>(conv_w, event_emb, conv_b, evconv);
  loc_kernel<<<(SZ * 600 + 255) / 256, 256, 0, stream>>>(loc, loc_mark, word_emb, out);
  dmcnn_main<<<SZ / G, 512, 0, stream>>>(inp, pos1, pos2, subtype,
      maskL, maskM, word_emb, pos_emb, wk, evconv, out);
}